// Round 4
// baseline (75.528 us; speedup 1.0000x reference)
//
#include <hip/hip_runtime.h>
#include <math.h>

#define NROWS 100000
#define CCOLS 1024
#define GRID  1024
#define BLOCK 256
#define WPB   (BLOCK / 64)   // waves per block

// Main kernel: one wave per row, grid-stride. Produces per-block partial sums
// of (z*logmax, r*logmax, z*dist) into partials[0..3*GRID).
__global__ __launch_bounds__(BLOCK) void bp_main(
    const float* __restrict__ cs,        // [N, C] class_scores
    const float* __restrict__ xywh,      // [N, 4]
    const float* __restrict__ z,         // [N]
    const float* __restrict__ r,         // [N]
    const int*   __restrict__ nearest,   // [N]
    const int*   __restrict__ gt_lbl,    // [M]
    const float* __restrict__ gt_xywh,   // [M, 4]
    float* __restrict__ partials,        // [3 * GRID]
    int n)
{
    const int lane  = threadIdx.x & 63;
    const int wave  = threadIdx.x >> 6;
    const int gwave = blockIdx.x * WPB + wave;
    const int nwav  = gridDim.x * WPB;

    float acc_z = 0.f, acc_r = 0.f, acc_d = 0.f;

    for (int row = gwave; row < n; row += nwav) {
        const int   gi    = nearest[row];
        const int   label = gt_lbl[gi];
        const float4* rowp = (const float4*)(cs + (size_t)row * CCOLS);

        // masked row always contains a 0 (the zeroed label column), and all
        // scores are >= 0, so starting the max at 0 matches the reference.
        float m = 0.f;
        #pragma unroll
        for (int k = 0; k < 4; ++k) {
            const int    idx   = lane + k * 64;   // float4 index within row
            const int    cbase = idx * 4;         // column of .x
            const float4 v     = rowp[idx];
            const float a = (cbase + 0 == label) ? 0.f : v.x;
            const float b = (cbase + 1 == label) ? 0.f : v.y;
            const float c = (cbase + 2 == label) ? 0.f : v.z;
            const float d = (cbase + 3 == label) ? 0.f : v.w;
            m = fmaxf(m, fmaxf(fmaxf(a, b), fmaxf(c, d)));
        }
        // 64-lane max reduction
        #pragma unroll
        for (int off = 32; off >= 1; off >>= 1)
            m = fmaxf(m, __shfl_xor(m, off, 64));

        if (lane == 0) {
            const float lm = logf(m);
            const float zi = z[row];
            const float ri = r[row];
            const float4 x = *(const float4*)(xywh    + (size_t)row * 4);
            const float4 g = *(const float4*)(gt_xywh + (size_t)gi  * 4);
            const float dx = x.x - g.x, dy = x.y - g.y,
                        dw = x.z - g.z, dh = x.w - g.w;
            const float dist = dx * dx + dy * dy + dw * dw + dh * dh;
            acc_z += zi * lm;
            acc_r += ri * lm;
            acc_d += zi * dist;
        }
    }

    __shared__ float s[WPB][3];
    if (lane == 0) { s[wave][0] = acc_z; s[wave][1] = acc_r; s[wave][2] = acc_d; }
    __syncthreads();
    if (threadIdx.x == 0) {
        float sz = 0.f, sr = 0.f, sd = 0.f;
        #pragma unroll
        for (int w = 0; w < WPB; ++w) { sz += s[w][0]; sr += s[w][1]; sd += s[w][2]; }
        partials[             blockIdx.x] = sz;
        partials[    GRID +  blockIdx.x] = sr;
        partials[2 * GRID +  blockIdx.x] = sd;
    }
}

// Final: single block reduces the GRID partials and writes the scalar.
__global__ __launch_bounds__(256) void bp_final(
    const float* __restrict__ partials, float* __restrict__ out)
{
    float sz = 0.f, sr = 0.f, sd = 0.f;
    for (int i = threadIdx.x; i < GRID; i += 256) {
        sz += partials[i];
        sr += partials[GRID + i];
        sd += partials[2 * GRID + i];
    }
    // wave reduce
    #pragma unroll
    for (int off = 32; off >= 1; off >>= 1) {
        sz += __shfl_xor(sz, off, 64);
        sr += __shfl_xor(sr, off, 64);
        sd += __shfl_xor(sd, off, 64);
    }
    __shared__ float sh[4][3];
    const int lane = threadIdx.x & 63;
    const int wave = threadIdx.x >> 6;
    if (lane == 0) { sh[wave][0] = sz; sh[wave][1] = sr; sh[wave][2] = sd; }
    __syncthreads();
    if (threadIdx.x == 0) {
        float tz = 0.f, tr = 0.f, td = 0.f;
        #pragma unroll
        for (int w = 0; w < 4; ++w) { tz += sh[w][0]; tr += sh[w][1]; td += sh[w][2]; }
        // tpc + tps + fpc = -tz + exp(-td) - tr
        out[0] = -tz - tr + expf(-td);
    }
}

extern "C" void kernel_launch(void* const* d_in, const int* in_sizes, int n_in,
                              void* d_out, int out_size, void* d_ws, size_t ws_size,
                              hipStream_t stream) {
    const float* cs      = (const float*)d_in[0];
    const float* xywh    = (const float*)d_in[1];
    const float* z       = (const float*)d_in[2];
    const float* r       = (const float*)d_in[3];
    const int*   nearest = (const int*)  d_in[4];
    const int*   gt_lbl  = (const int*)  d_in[5];
    const float* gt_xywh = (const float*)d_in[6];
    float* out = (float*)d_out;
    float* partials = (float*)d_ws;     // needs 3*GRID*4 = 12 KB
    const int n = in_sizes[2];          // N (z has N elements)

    bp_main<<<GRID, BLOCK, 0, stream>>>(cs, xywh, z, r, nearest, gt_lbl,
                                        gt_xywh, partials, n);
    bp_final<<<1, 256, 0, stream>>>(partials, out);
}